// Round 8
// baseline (1348.971 us; speedup 1.0000x reference)
//
#include <hip/hip_runtime.h>
#include <cstdint>
#include <cstddef>

#define B_ROWS 32768
#define ZD 64
#define XD 256
#define HID 512
#define T_STEPS 8
#define MULT 23
#define MPAD 24
#define NOUT 1472
#define NPAD 1536      // 64 * MPAD
#define K1 320         // ZD + XD
#define PSTRIDE 200    // padded row stride (ushorts) for p half-tile in LDS
#define ASTRIDE 520    // A-cache row stride in ushorts: 1040 B = 16B-aligned,
                       // 260 words ≡ 4 mod 32 -> conflict-floor fragment reads

typedef float f32x4 __attribute__((ext_vector_type(4)));
typedef short s16x8 __attribute__((ext_vector_type(8)));

__device__ __forceinline__ unsigned short f2bf(float f) {
  unsigned int u = __float_as_uint(f);
  u = (u + 0x7FFFu + ((u >> 16) & 1u)) >> 16;   // RNE, no NaN inputs here
  return (unsigned short)u;
}
__device__ __forceinline__ float bf2f(unsigned short s) {
  return __uint_as_float(((unsigned int)s) << 16);
}

// Degree-sort permutation of the hidden dim. deg(i) = (i%63)+1; count(g) = 9 (g<=8) else 8.
__device__ __forceinline__ int permP(int n) {
  return (n < 72) ? (n / 9) + 63 * (n % 9)
                  : ((n - 72) >> 3) + 8 + 63 * ((n - 72) & 7);
}
__device__ __forceinline__ int degP(int n) {
  return (n < 72) ? (n / 9) + 1 : ((n - 72) >> 3) + 9;
}

// ---------------- merged prep kernels ----------------

__global__ void prep_weights(const float* __restrict__ W1, const float* __restrict__ Wc,
                             const float* __restrict__ W2, const float* __restrict__ W3,
                             const float* __restrict__ b1, const float* __restrict__ bc,
                             const float* __restrict__ b2, const float* __restrict__ b3,
                             unsigned short* __restrict__ w1c, unsigned short* __restrict__ w2c,
                             unsigned short* __restrict__ w3c,
                             float* __restrict__ ob1, float* __restrict__ ob2,
                             float* __restrict__ ob3) {
  const int S1 = T_STEPS * HID * K1;
  const int S2 = S1 + T_STEPS * HID * HID;
  const int S3 = S2 + T_STEPS * NPAD * HID;
  const int S4 = S3 + T_STEPS * HID;
  const int S5 = S4 + T_STEPS * HID;
  const int S6 = S5 + T_STEPS * NPAD;
  int i = blockIdx.x * 256 + threadIdx.x;
  if (i < S1) {
    int t = i / (HID * K1);
    int r = i - t * (HID * K1);
    int n = r / K1;          // permuted hidden row
    int k = r - n * K1;
    int on = permP(n);
    float v;
    if (k < ZD) v = ((on % 63) >= k) ? W1[((size_t)t * HID + on) * ZD + k] : 0.0f;
    else        v = Wc[((size_t)t * HID + on) * XD + (k - ZD)];
    w1c[i] = f2bf(v);
  } else if (i < S2) {
    int j = i - S1;
    int t = j / (HID * HID);
    int r = j - t * (HID * HID);
    int n = r / HID;
    int k = r - n * HID;
    float v = 0.0f;
    if (degP(n) >= degP(k))
      v = W2[((size_t)t * HID + permP(n)) * HID + permP(k)];
    w2c[j] = f2bf(v);
  } else if (i < S3) {
    int j = i - S2;
    int t = j / (NPAD * HID);
    int r = j - t * (NPAD * HID);
    int n = r / HID;
    int k = r - n * HID;
    int d = n / MPAD;
    int jj = n - d * MPAD;
    float v = 0.0f;
    if (jj < MULT && d >= degP(k))
      v = W3[((size_t)t * NOUT + d * MULT + jj) * HID + permP(k)];
    w3c[j] = f2bf(v);
  } else if (i < S4) {
    int j = i - S3;
    int t = j / HID, n = j - t * HID;
    int on = permP(n);
    ob1[j] = b1[(size_t)t * HID + on] + bc[(size_t)t * HID + on];
  } else if (i < S5) {
    int j = i - S4;
    int t = j / HID, n = j - t * HID;
    ob2[j] = b2[(size_t)t * HID + permP(n)];
  } else if (i < S6) {
    int j = i - S5;
    int t = j / NPAD;
    int n = j - t * NPAD;
    int d = n / MPAD;
    int jj = n - d * MPAD;
    ob3[j] = (jj < MULT) ? b3[(size_t)t * NOUT + d * MULT + jj] : 0.0f;
  }
}

__global__ void prep_data(const float* __restrict__ x, const float* __restrict__ z,
                          unsigned short* __restrict__ A1,
                          float* __restrict__ curf, float* __restrict__ out) {
  const int SX = B_ROWS * XD;
  int i = blockIdx.x * 256 + threadIdx.x;
  if (i < SX) {
    int b = i >> 8;
    int j = i & 255;
    A1[(size_t)b * K1 + ZD + j] = f2bf(x[i]);
  } else {
    int j = i - SX;
    if (j < B_ROWS * ZD) {
      int b = j >> 6;
      int d = j & 63;
      float zv = z[j];
      A1[(size_t)b * K1 + d] = f2bf(zv);
      curf[j] = zv;
      if (d == 0) out[b] = -58.81206612509905f;   // -0.5*64*ln(2pi); lad accumulates here
    }
  }
}

// ---------------- shared GEMM machinery ----------------

#define ASYNC16(gp, lp) __builtin_amdgcn_global_load_lds( \
    (__attribute__((address_space(1))) unsigned int*)(gp), \
    (__attribute__((address_space(3))) unsigned int*)(lp), 16, 0, 0)

#define WAITV(n) asm volatile("s_waitcnt vmcnt(" #n ")" ::: "memory")

// ---------------- GEMM1/2: C[M,512] = A[M,K]@W[512,K]^T + bias, opt relu ----------
// grid MUST be (4, 256). BK=32, 3-slot circular pipeline with counted vmcnt
// (T3+T4): slots k+1,k+2 stay in flight across barriers; vmcnt never drains
// to 0 in the main loop. 4 loads/slot -> steady-state wait vmcnt(8).

__global__ __launch_bounds__(256, 3) void gemm_bias(
    const unsigned short* __restrict__ A,
    const unsigned short* __restrict__ Bw,
    const float* __restrict__ bias,
    unsigned short* __restrict__ C,
    int M, int N, int K, int relu, int tri)
{
  __shared__ alignas(16) unsigned short lS[3][8192];   // per slot: A 128x32 | B 128x32

  const int tid  = threadIdx.x;
  const int lane = tid & 63;
  const int wave = tid >> 6;

  const int lin = blockIdx.y * 4 + blockIdx.x;
  const int xcd = lin & 7;
  const int loc = lin >> 3;
  const int m0 = (xcd * 32 + (loc >> 2)) * 128;
  const int n0 = (loc & 3) * 128;
  const int Keff = tri ? min(K, 192 + n0) : K;
  const int nIter = Keff >> 5;     // BK=32; all Keff are multiples of 64

  const int wm = (wave >> 1) * 64;
  const int wn = (wave & 1) * 64;

  const int f    = tid * 16;
  const int row0 = f >> 6;       // 64B per 32-elem row
  const int colb = f & 63;

  char* gA0 = (char*)A  + ((size_t)(m0 + row0) * K) * 2 + colb;
  char* gA1 = gA0 + (size_t)64 * K * 2;
  char* gB0 = (char*)Bw + ((size_t)(n0 + row0) * K) * 2 + colb;
  char* gB1 = gB0 + (size_t)64 * K * 2;

  f32x4 acc[4][4];
#pragma unroll
  for (int i = 0; i < 4; i++)
#pragma unroll
    for (int j = 0; j < 4; j++) acc[i][j] = (f32x4){0.f, 0.f, 0.f, 0.f};

  const int fr = lane & 15;
  const int fk = (lane >> 4) * 8;   // k offset in shorts within a 32-k row

#define STAGEB(sp) do { \
    unsigned short* s_ = (sp) + wave * 512; \
    ASYNC16(gA0, s_); \
    ASYNC16(gA1, s_ + 2048); \
    ASYNC16(gB0, s_ + 4096); \
    ASYNC16(gB1, s_ + 6144); \
    gA0 += 64; gA1 += 64; gB0 += 64; gB1 += 64; \
  } while (0)

  STAGEB(lS[0]);
  STAGEB(lS[1]);

  for (int k = 0; k < nIter; ++k) {
    __builtin_amdgcn_sched_barrier(0);
    if (k + 2 < nIter) STAGEB(lS[0] + ((k + 2) % 3) * 8192);
    const int nv = nIter - 1 - k;
    if (nv >= 2)      WAITV(8);   // slots k+1,k+2 in flight
    else if (nv == 1) WAITV(4);   // slot k+1 in flight
    else              WAITV(0);   // tail: drain
    __builtin_amdgcn_s_barrier();
    __builtin_amdgcn_sched_barrier(0);

    const unsigned short* cs = lS[0] + (k % 3) * 8192;
    s16x8 a[4], b[4];
#pragma unroll
    for (int i = 0; i < 4; i++)
      a[i] = *(const s16x8*)(cs + (wm + i * 16 + fr) * 32 + fk);
#pragma unroll
    for (int j = 0; j < 4; j++)
      b[j] = *(const s16x8*)(cs + 4096 + (wn + j * 16 + fr) * 32 + fk);

#pragma unroll
    for (int i = 0; i < 4; i++)
#pragma unroll
      for (int j = 0; j < 4; j++)
        acc[i][j] = __builtin_amdgcn_mfma_f32_16x16x32_bf16(a[i], b[j], acc[i][j], 0, 0, 0);

    __builtin_amdgcn_sched_barrier(0);
    __builtin_amdgcn_s_barrier();   // all waves done reading slot k -> reusable
  }
#undef STAGEB

#pragma unroll
  for (int j = 0; j < 4; j++) {
    const int col = n0 + wn + j * 16 + fr;
    const float bv = bias[col];
#pragma unroll
    for (int i = 0; i < 4; i++) {
      const int rbase = m0 + wm + i * 16 + (lane >> 4) * 4;
#pragma unroll
      for (int r = 0; r < 4; r++) {
        float v = acc[i][j][r] + bv;
        if (relu) v = fmaxf(v, 0.0f);
        C[(size_t)(rbase + r) * N + col] = f2bf(v);
      }
    }
  }
}

// ---------------- spline math (per (b,d)) ----------------

__device__ __forceinline__ void rq_spline(const unsigned short* __restrict__ pp,
                                          float zv, float& zn, float& lad) {
  const float TAILC = 25.0f;
  const float MIN_WC = 0.001f;
  const float MIN_DC = 0.001f;
  // exp2-folded scale: (1/sqrt(512)) * log2(e)
  const float SCALE2 = 0.06376007120095582f;
  const float LN2 = 0.6931471805599453f;

  s16x8 vw = *(const s16x8*)(pp);
  s16x8 vh = *(const s16x8*)(pp + 8);
  s16x8 vd = *(const s16x8*)(pp + 16);

  bool inside = (zv >= -TAILC) && (zv <= TAILC);
  float z_in = fminf(fmaxf(zv, -TAILC), TAILC);

  // softmax without max-pass or clamps: |params*scale| << 1 here.
  float ew[8], eh[8], sw = 0.f, sh = 0.f;
#pragma unroll
  for (int i = 0; i < 8; i++) {
    ew[i] = exp2f(bf2f((unsigned short)vw[i]) * SCALE2); sw += ew[i];
  }
#pragma unroll
  for (int i = 0; i < 8; i++) {
    eh[i] = exp2f(bf2f((unsigned short)vh[i]) * SCALE2); sh += eh[i];
  }
  float iw = (1.0f - 8.0f * MIN_WC) / sw;
  float ih = (1.0f - 8.0f * MIN_WC) / sh;

  float cumw[9], cumh[9];
  cumw[0] = -TAILC; cumh[0] = -TAILC;
  float cw = 0.f, ch = 0.f;
#pragma unroll
  for (int i = 0; i < 8; i++) {
    cw += MIN_WC + ew[i] * iw;
    ch += MIN_WC + eh[i] * ih;
    cumw[i + 1] = fmaf(2.0f * TAILC, cw, -TAILC);
    cumh[i + 1] = fmaf(2.0f * TAILC, ch, -TAILC);
  }
  cumw[8] = TAILC; cumh[8] = TAILC;

  int idx = 0;
#pragma unroll
  for (int i = 1; i < 8; i++) idx += (z_in >= cumw[i]) ? 1 : 0;

  float in_cw = 0.f, cw1 = 1.f, in_ch = 0.f, ch1 = 1.f, u0 = 0.f, u1 = 0.f;
#pragma unroll
  for (int i = 0; i < 8; i++) {
    if (i == idx) {
      in_cw = cumw[i]; cw1 = cumw[i + 1];
      in_ch = cumh[i]; ch1 = cumh[i + 1];
      u0 = (i > 0) ? bf2f((unsigned short)vd[i - 1]) : 0.0f;
      u1 = (i < 7) ? bf2f((unsigned short)vd[i]) : 0.0f;
    }
  }
  float dd0 = (idx == 0) ? 1.0f
            : MIN_DC + fmaxf(u0, 0.f) + __logf(1.0f + __expf(-fabsf(u0)));
  float dd1 = (idx == 7) ? 1.0f
            : MIN_DC + fmaxf(u1, 0.f) + __logf(1.0f + __expf(-fabsf(u1)));
  float in_w = cw1 - in_cw;
  float in_h = ch1 - in_ch;

  float delta = in_h / in_w;
  float th  = (z_in - in_cw) / in_w;
  float th1 = th * (1.0f - th);
  float th2 = th * th;
  float num = in_h * (delta * th2 + dd0 * th1);
  float den = delta + (dd0 + dd1 - 2.0f * delta) * th1;
  float outz = in_ch + num / den;
  float omt = 1.0f - th;
  float dnum = delta * delta * (dd1 * th2 + 2.0f * delta * th1 + dd0 * omt * omt);
  float l = LN2 * (__log2f(dnum) - 2.0f * __log2f(den));

  zn  = inside ? outz : zv;
  lad = inside ? l : 0.0f;
}

// ---------------- fused GEMM3 + spline: MERGED-bn, one block per m-tile ---------
// grid MUST be (256). One block owns the full 128 rows x 1536 (all 8 bn
// sub-tiles), looping bn = 0..7 with K_eff = 64*(bn+1).
// A-tile (h2 128x512) cached in LDS ONCE (padded stride 520 shorts, 133KB);
// per-iter staging is B-only (6 DMA/thread, single slot, R1 layout) unioned
// with a 64-row p half-tile (25.6KB). LDS total 158,720 B -> 1 block/CU.
// K-loop body = R1's proven BK=64 2-barrier form, 36 iters/block.
// lad accumulates in registers across bn; ONE atomicAdd per row-half at end.

__global__ __launch_bounds__(256, 1) void gemm3_spline(
    const unsigned short* __restrict__ A,     // h2 [B][512] (k degree-permuted)
    const unsigned short* __restrict__ Bw,    // w3c[t] [1536][512] (MPAD rows, perm k)
    const float* __restrict__ bias,           // [1536] (MPAD layout)
    float* __restrict__ curf,                 // [B][64]
    unsigned short* __restrict__ A1,          // [B][320]
    float* __restrict__ out,                  // [B] accumulator (= final output)
    int last)
{
  __shared__ alignas(16) unsigned short Ac[128 * ASTRIDE];         // 133,120 B
  __shared__ alignas(16) union {
    unsigned short B[2 * 192 * 32];                                // 24,576 B
    unsigned short p[64 * PSTRIDE];                                // 25,600 B
  } sm;

  const int tid  = threadIdx.x;
  const int lane = tid & 63;
  const int wave = tid >> 6;
  const int m0   = blockIdx.x * 128;

  // ---- A-cache DMA: one wave-call per row (wave-uniform LDS base; per-lane
  // global src = rowbase + lane*16; HW writes base + lane*16 -> exact row fill).
  {
    const char* gA = (const char*)A + ((size_t)m0 << 10) + lane * 16;
#pragma unroll
    for (int s = 0; s < 32; ++s) {
      const int row = wave + s * 4;   // wave-uniform per call
      ASYNC16(gA + ((size_t)row << 10), (char*)Ac + row * (ASTRIDE * 2));
    }
  }
  // first K-loop __syncthreads drains this (compiler emits vmcnt(0) there).

  const int wm = (wave >> 1) * 64;
  const int wn = (wave & 1) * 96;
  const int fr = lane & 15;
  const int fk = (lane >> 4) * 8;

  const int srow64 = tid & 63;
  const int dloc   = wave * 2;           // spline dims dloc, dloc+1 (0..7)

  const int f    = tid * 16;
  const int row0 = f >> 6;               // 0..63 (64B per 32-elem row)
  const int colb = f & 63;

  float la0 = 0.f, la1 = 0.f;            // reg-accumulated lad per row-half

  for (int bn = 0; bn < 8; ++bn) {
    const int n0 = bn * 192;
    const int dglob = bn * 8 + dloc;
    // z inputs for this bn's dims (written by the PREVIOUS step's kernel)
    float2 cz0 = *(const float2*)(curf + (size_t)(m0 + srow64) * ZD + dglob);
    float2 cz1 = *(const float2*)(curf + (size_t)(m0 + 64 + srow64) * ZD + dglob);
    float bv[6];
#pragma unroll
    for (int j = 0; j < 6; j++) bv[j] = bias[n0 + wn + j * 16 + fr];

    char* gB0 = (char*)Bw + (((size_t)(n0 + row0)) << 10) + colb;
    char* gB1 = gB0 + ((size_t)64 << 10);
    char* gB2 = gB1 + ((size_t)64 << 10);
    unsigned short* lB0 = sm.B + wave * 512;
    unsigned short* lB1 = sm.B + 2048 + wave * 512;
    unsigned short* lB2 = sm.B + 4096 + wave * 512;

    f32x4 acc[4][6];
#pragma unroll
    for (int i = 0; i < 4; i++)
#pragma unroll
      for (int j = 0; j < 6; j++) acc[i][j] = (f32x4){0.f, 0.f, 0.f, 0.f};

    const int Keff = 64 * (bn + 1);
    for (int k0 = 0; k0 < Keff; k0 += 64) {
      ASYNC16(gB0, lB0);
      ASYNC16(gB1, lB1);
      ASYNC16(gB2, lB2);
      ASYNC16(gB0 + 64, lB0 + 6144);
      ASYNC16(gB1 + 64, lB1 + 6144);
      ASYNC16(gB2 + 64, lB2 + 6144);
      gB0 += 128; gB1 += 128; gB2 += 128;
      __syncthreads();

      s16x8 a0[4], a1[4], b0[6], b1[6];
#pragma unroll
      for (int i = 0; i < 4; i++) {
        const unsigned short* ar = Ac + (wm + i * 16 + fr) * ASTRIDE + k0 + fk;
        a0[i] = *(const s16x8*)(ar);
        a1[i] = *(const s16x8*)(ar + 32);
      }
#pragma unroll
      for (int j = 0; j < 6; j++) {
        b0[j] = *(const s16x8*)(sm.B + (wn + j * 16 + fr) * 32 + fk);
        b1[j] = *(const s16x8*)(sm.B + 6144 + (wn + j * 16 + fr) * 32 + fk);
      }

#pragma unroll
      for (int i = 0; i < 4; i++)
#pragma unroll
        for (int j = 0; j < 6; j++)
          acc[i][j] = __builtin_amdgcn_mfma_f32_16x16x32_bf16(a0[i], b0[j], acc[i][j], 0, 0, 0);
#pragma unroll
      for (int i = 0; i < 4; i++)
#pragma unroll
        for (int j = 0; j < 6; j++)
          acc[i][j] = __builtin_amdgcn_mfma_f32_16x16x32_bf16(a1[i], b1[j], acc[i][j], 0, 0, 0);
      __syncthreads();
    }

    // ---- epilogue for this bn: two 64-row phases (p half-tile unions B slot)
#pragma unroll
    for (int h = 0; h < 2; ++h) {
      if ((wave >> 1) == h) {
#pragma unroll
        for (int j = 0; j < 6; j++) {
          const int col = wn + j * 16 + fr;
#pragma unroll
          for (int i = 0; i < 4; i++) {
            const int rloc = i * 16 + (lane >> 4) * 4;
#pragma unroll
            for (int r = 0; r < 4; r++)
              sm.p[(rloc + r) * PSTRIDE + col] = f2bf(acc[i][j][r] + bv[j]);
          }
        }
      }
      __syncthreads();

      {
        const int sbr = m0 + h * 64 + srow64;
        const float2 czv = h ? cz1 : cz0;
        const unsigned short* pp = sm.p + srow64 * PSTRIDE + dloc * MPAD;
        float zn0, zn1, l0, l1;
        rq_spline(pp,        czv.x, zn0, l0);
        rq_spline(pp + MPAD, czv.y, zn1, l1);

        *(float2*)(curf + (size_t)sbr * ZD + dglob) = make_float2(zn0, zn1);
        unsigned int pkv = (unsigned int)f2bf(zn0) | ((unsigned int)f2bf(zn1) << 16);
        *(unsigned int*)(A1 + (size_t)sbr * K1 + dglob) = pkv;

        float c = l0 + l1;
        if (last) c -= 0.5f * (zn0 * zn0 + zn1 * zn1);
        if (h == 0) la0 += c; else la1 += c;
      }
      __syncthreads();   // protects p before overwrite (h=0) / B restage (h=1)
    }
  }

  atomicAdd(&out[m0 + srow64], la0);
  atomicAdd(&out[m0 + 64 + srow64], la1);
}

// ---------------- launch ----------------

extern "C" void kernel_launch(void* const* d_in, const int* in_sizes, int n_in,
                              void* d_out, int out_size, void* d_ws, size_t ws_size,
                              hipStream_t stream)
{
  const float* z  = (const float*)d_in[0];
  const float* x  = (const float*)d_in[1];
  const float* W1 = (const float*)d_in[2];
  const float* b1 = (const float*)d_in[3];
  const float* Wc = (const float*)d_in[4];
  const float* bc = (const float*)d_in[5];
  const float* W2 = (const float*)d_in[6];
  const float* b2 = (const float*)d_in[7];
  const float* W3 = (const float*)d_in[8];
  const float* b3 = (const float*)d_in[9];
  float* out = (float*)d_out;
  char* ws = (char*)d_ws;

  size_t oA1 = 0;
  size_t oH1 = oA1 + (size_t)B_ROWS * K1 * 2;
  size_t oH2 = oH1 + (size_t)B_ROWS * HID * 2;
  size_t oCU = oH2 + (size_t)B_ROWS * HID * 2;
  size_t oW1 = oCU + (size_t)B_ROWS * ZD * 4;
  size_t oW2 = oW1 + (size_t)T_STEPS * HID * K1 * 2;
  size_t oW3 = oW2 + (size_t)T_STEPS * HID * HID * 2;
  size_t oB1 = oW3 + (size_t)T_STEPS * NPAD * HID * 2;
  size_t oB2 = oB1 + (size_t)T_STEPS * HID * 4;
  size_t oB3 = oB2 + (size_t)T_STEPS * HID * 4;

  unsigned short* A1  = (unsigned short*)(ws + oA1);
  unsigned short* h1  = (unsigned short*)(ws + oH1);
  unsigned short* h2  = (unsigned short*)(ws + oH2);
  float* curf = (float*)(ws + oCU);
  unsigned short* w1c = (unsigned short*)(ws + oW1);
  unsigned short* w2c = (unsigned short*)(ws + oW2);
  unsigned short* w3c = (unsigned short*)(ws + oW3);
  float* b1c = (float*)(ws + oB1);
  float* b2p = (float*)(ws + oB2);
  float* b3c = (float*)(ws + oB3);

  const int prepw_total = T_STEPS * (HID * K1 + HID * HID + NPAD * HID + 2 * HID + NPAD);
  prep_weights<<<(prepw_total + 255) / 256, 256, 0, stream>>>(
      W1, Wc, W2, W3, b1, bc, b2, b3, w1c, w2c, w3c, b1c, b2p, b3c);
  const int prepd_total = B_ROWS * (XD + ZD);
  prep_data<<<(prepd_total + 255) / 256, 256, 0, stream>>>(x, z, A1, curf, out);

  for (int t = 0; t < T_STEPS; ++t) {
    gemm_bias<<<dim3(4, B_ROWS / 128), 256, 0, stream>>>(
        A1, w1c + (size_t)t * HID * K1, b1c + (size_t)t * HID, h1,
        B_ROWS, HID, K1, 0, 0);
    gemm_bias<<<dim3(4, B_ROWS / 128), 256, 0, stream>>>(
        h1, w2c + (size_t)t * HID * HID, b2p + (size_t)t * HID, h2,
        B_ROWS, HID, HID, 1, 1);
    gemm3_spline<<<dim3(B_ROWS / 128), 256, 0, stream>>>(
        h2, w3c + (size_t)t * NPAD * HID, b3c + (size_t)t * NPAD,
        curf, A1, out, (t == T_STEPS - 1) ? 1 : 0);
  }
}

// Round 9
// 1002.559 us; speedup vs baseline: 1.3455x; 1.3455x over previous
//
#include <hip/hip_runtime.h>
#include <cstdint>
#include <cstddef>

#define B_ROWS 32768
#define ZD 64
#define XD 256
#define HID 512
#define T_STEPS 8
#define MULT 23
#define MPAD 24
#define NOUT 1472
#define NPAD 1536      // 64 * MPAD
#define K1 320         // ZD + XD
#define PSTRIDE 200    // padded row stride (ushorts) for p-tile in LDS
                       // 400 B/row: 16B-aligned; word-stride 100 ≡ 4 mod 32.

typedef float f32x4 __attribute__((ext_vector_type(4)));
typedef short s16x8 __attribute__((ext_vector_type(8)));

__device__ __forceinline__ unsigned short f2bf(float f) {
  unsigned int u = __float_as_uint(f);
  u = (u + 0x7FFFu + ((u >> 16) & 1u)) >> 16;   // RNE, no NaN inputs here
  return (unsigned short)u;
}
__device__ __forceinline__ float bf2f(unsigned short s) {
  return __uint_as_float(((unsigned int)s) << 16);
}

// Degree-sort permutation of the hidden dim. deg(i) = (i%63)+1; count(g) = 9 (g<=8) else 8.
__device__ __forceinline__ int permP(int n) {
  return (n < 72) ? (n / 9) + 63 * (n % 9)
                  : ((n - 72) >> 3) + 8 + 63 * ((n - 72) & 7);
}
__device__ __forceinline__ int degP(int n) {
  return (n < 72) ? (n / 9) + 1 : ((n - 72) >> 3) + 9;
}

// ---------------- merged prep kernels ----------------

__global__ void prep_weights(const float* __restrict__ W1, const float* __restrict__ Wc,
                             const float* __restrict__ W2, const float* __restrict__ W3,
                             const float* __restrict__ b1, const float* __restrict__ bc,
                             const float* __restrict__ b2, const float* __restrict__ b3,
                             unsigned short* __restrict__ w1c, unsigned short* __restrict__ w2c,
                             unsigned short* __restrict__ w3c,
                             float* __restrict__ ob1, float* __restrict__ ob2,
                             float* __restrict__ ob3) {
  const int S1 = T_STEPS * HID * K1;
  const int S2 = S1 + T_STEPS * HID * HID;
  const int S3 = S2 + T_STEPS * NPAD * HID;
  const int S4 = S3 + T_STEPS * HID;
  const int S5 = S4 + T_STEPS * HID;
  const int S6 = S5 + T_STEPS * NPAD;
  int i = blockIdx.x * 256 + threadIdx.x;
  if (i < S1) {
    int t = i / (HID * K1);
    int r = i - t * (HID * K1);
    int n = r / K1;          // permuted hidden row
    int k = r - n * K1;
    int on = permP(n);
    float v;
    if (k < ZD) v = ((on % 63) >= k) ? W1[((size_t)t * HID + on) * ZD + k] : 0.0f;
    else        v = Wc[((size_t)t * HID + on) * XD + (k - ZD)];
    w1c[i] = f2bf(v);
  } else if (i < S2) {
    int j = i - S1;
    int t = j / (HID * HID);
    int r = j - t * (HID * HID);
    int n = r / HID;
    int k = r - n * HID;
    float v = 0.0f;
    if (degP(n) >= degP(k))
      v = W2[((size_t)t * HID + permP(n)) * HID + permP(k)];
    w2c[j] = f2bf(v);
  } else if (i < S3) {
    int j = i - S2;
    int t = j / (NPAD * HID);
    int r = j - t * (NPAD * HID);
    int n = r / HID;
    int k = r - n * HID;
    int d = n / MPAD;
    int jj = n - d * MPAD;
    float v = 0.0f;
    if (jj < MULT && d >= degP(k))
      v = W3[((size_t)t * NOUT + d * MULT + jj) * HID + permP(k)];
    w3c[j] = f2bf(v);
  } else if (i < S4) {
    int j = i - S3;
    int t = j / HID, n = j - t * HID;
    int on = permP(n);
    ob1[j] = b1[(size_t)t * HID + on] + bc[(size_t)t * HID + on];
  } else if (i < S5) {
    int j = i - S4;
    int t = j / HID, n = j - t * HID;
    ob2[j] = b2[(size_t)t * HID + permP(n)];
  } else if (i < S6) {
    int j = i - S5;
    int t = j / NPAD;
    int n = j - t * NPAD;
    int d = n / MPAD;
    int jj = n - d * MPAD;
    ob3[j] = (jj < MULT) ? b3[(size_t)t * NOUT + d * MULT + jj] : 0.0f;
  }
}

__global__ void prep_data(const float* __restrict__ x, const float* __restrict__ z,
                          unsigned short* __restrict__ A1,
                          float* __restrict__ curf, float* __restrict__ out) {
  const int SX = B_ROWS * XD;
  int i = blockIdx.x * 256 + threadIdx.x;
  if (i < SX) {
    int b = i >> 8;
    int j = i & 255;
    A1[(size_t)b * K1 + ZD + j] = f2bf(x[i]);
  } else {
    int j = i - SX;
    if (j < B_ROWS * ZD) {
      int b = j >> 6;
      int d = j & 63;
      float zv = z[j];
      A1[(size_t)b * K1 + d] = f2bf(zv);
      curf[j] = zv;
      if (d == 0) out[b] = -58.81206612509905f;   // -0.5*64*ln(2pi); lad accumulates here
    }
  }
}

// ---------------- shared GEMM machinery ----------------

#define ASYNC16(gp, lp) __builtin_amdgcn_global_load_lds( \
    (__attribute__((address_space(1))) unsigned int*)(gp), \
    (__attribute__((address_space(3))) unsigned int*)(lp), 16, 0, 0)

#define WAITV(n) asm volatile("s_waitcnt vmcnt(" #n ")" ::: "memory")

// ---------------- GEMM1/2: C[M,512] = A[M,K]@W[512,K]^T + bias, opt relu ----------
// grid MUST be (4, 256). BK=32, 3-slot circular pipeline with counted vmcnt
// (T3+T4): slots k+1,k+2 stay in flight across barriers; vmcnt never drains
// to 0 in the main loop. 4 loads/slot -> steady-state wait vmcnt(8).

__global__ __launch_bounds__(256, 3) void gemm_bias(
    const unsigned short* __restrict__ A,
    const unsigned short* __restrict__ Bw,
    const float* __restrict__ bias,
    unsigned short* __restrict__ C,
    int M, int N, int K, int relu, int tri)
{
  __shared__ alignas(16) unsigned short lS[3][8192];   // per slot: A 128x32 | B 128x32

  const int tid  = threadIdx.x;
  const int lane = tid & 63;
  const int wave = tid >> 6;

  const int lin = blockIdx.y * 4 + blockIdx.x;
  const int xcd = lin & 7;
  const int loc = lin >> 3;
  const int m0 = (xcd * 32 + (loc >> 2)) * 128;
  const int n0 = (loc & 3) * 128;
  const int Keff = tri ? min(K, 192 + n0) : K;
  const int nIter = Keff >> 5;     // BK=32; all Keff are multiples of 64

  const int wm = (wave >> 1) * 64;
  const int wn = (wave & 1) * 64;

  const int f    = tid * 16;
  const int row0 = f >> 6;       // 64B per 32-elem row
  const int colb = f & 63;

  char* gA0 = (char*)A  + ((size_t)(m0 + row0) * K) * 2 + colb;
  char* gA1 = gA0 + (size_t)64 * K * 2;
  char* gB0 = (char*)Bw + ((size_t)(n0 + row0) * K) * 2 + colb;
  char* gB1 = gB0 + (size_t)64 * K * 2;

  f32x4 acc[4][4];
#pragma unroll
  for (int i = 0; i < 4; i++)
#pragma unroll
    for (int j = 0; j < 4; j++) acc[i][j] = (f32x4){0.f, 0.f, 0.f, 0.f};

  const int fr = lane & 15;
  const int fk = (lane >> 4) * 8;   // k offset in shorts within a 32-k row

#define STAGEB(sp) do { \
    unsigned short* s_ = (sp) + wave * 512; \
    ASYNC16(gA0, s_); \
    ASYNC16(gA1, s_ + 2048); \
    ASYNC16(gB0, s_ + 4096); \
    ASYNC16(gB1, s_ + 6144); \
    gA0 += 64; gA1 += 64; gB0 += 64; gB1 += 64; \
  } while (0)

  STAGEB(lS[0]);
  STAGEB(lS[1]);

  for (int k = 0; k < nIter; ++k) {
    __builtin_amdgcn_sched_barrier(0);
    if (k + 2 < nIter) STAGEB(lS[0] + ((k + 2) % 3) * 8192);
    const int nv = nIter - 1 - k;
    if (nv >= 2)      WAITV(8);   // slots k+1,k+2 in flight
    else if (nv == 1) WAITV(4);   // slot k+1 in flight
    else              WAITV(0);   // tail: drain
    __builtin_amdgcn_s_barrier();
    __builtin_amdgcn_sched_barrier(0);

    const unsigned short* cs = lS[0] + (k % 3) * 8192;
    s16x8 a[4], b[4];
#pragma unroll
    for (int i = 0; i < 4; i++)
      a[i] = *(const s16x8*)(cs + (wm + i * 16 + fr) * 32 + fk);
#pragma unroll
    for (int j = 0; j < 4; j++)
      b[j] = *(const s16x8*)(cs + 4096 + (wn + j * 16 + fr) * 32 + fk);

#pragma unroll
    for (int i = 0; i < 4; i++)
#pragma unroll
      for (int j = 0; j < 4; j++)
        acc[i][j] = __builtin_amdgcn_mfma_f32_16x16x32_bf16(a[i], b[j], acc[i][j], 0, 0, 0);

    __builtin_amdgcn_sched_barrier(0);
    __builtin_amdgcn_s_barrier();   // all waves done reading slot k -> reusable
  }
#undef STAGEB

#pragma unroll
  for (int j = 0; j < 4; j++) {
    const int col = n0 + wn + j * 16 + fr;
    const float bv = bias[col];
#pragma unroll
    for (int i = 0; i < 4; i++) {
      const int rbase = m0 + wm + i * 16 + (lane >> 4) * 4;
#pragma unroll
      for (int r = 0; r < 4; r++) {
        float v = acc[i][j][r] + bv;
        if (relu) v = fmaxf(v, 0.0f);
        C[(size_t)(rbase + r) * N + col] = f2bf(v);
      }
    }
  }
}

// ---------------- spline math (per (b,d)) ----------------

__device__ __forceinline__ void rq_spline(const unsigned short* __restrict__ pp,
                                          float zv, float& zn, float& lad) {
  const float TAILC = 25.0f;
  const float MIN_WC = 0.001f;
  const float MIN_DC = 0.001f;
  // exp2-folded scale: (1/sqrt(512)) * log2(e)
  const float SCALE2 = 0.06376007120095582f;
  const float LN2 = 0.6931471805599453f;

  s16x8 vw = *(const s16x8*)(pp);
  s16x8 vh = *(const s16x8*)(pp + 8);
  s16x8 vd = *(const s16x8*)(pp + 16);

  bool inside = (zv >= -TAILC) && (zv <= TAILC);
  float z_in = fminf(fmaxf(zv, -TAILC), TAILC);

  // softmax without max-pass or clamps: |params*scale| << 1 here.
  float ew[8], eh[8], sw = 0.f, sh = 0.f;
#pragma unroll
  for (int i = 0; i < 8; i++) {
    ew[i] = exp2f(bf2f((unsigned short)vw[i]) * SCALE2); sw += ew[i];
  }
#pragma unroll
  for (int i = 0; i < 8; i++) {
    eh[i] = exp2f(bf2f((unsigned short)vh[i]) * SCALE2); sh += eh[i];
  }
  float iw = (1.0f - 8.0f * MIN_WC) / sw;
  float ih = (1.0f - 8.0f * MIN_WC) / sh;

  float cumw[9], cumh[9];
  cumw[0] = -TAILC; cumh[0] = -TAILC;
  float cw = 0.f, ch = 0.f;
#pragma unroll
  for (int i = 0; i < 8; i++) {
    cw += MIN_WC + ew[i] * iw;
    ch += MIN_WC + eh[i] * ih;
    cumw[i + 1] = fmaf(2.0f * TAILC, cw, -TAILC);
    cumh[i + 1] = fmaf(2.0f * TAILC, ch, -TAILC);
  }
  cumw[8] = TAILC; cumh[8] = TAILC;

  int idx = 0;
#pragma unroll
  for (int i = 1; i < 8; i++) idx += (z_in >= cumw[i]) ? 1 : 0;

  float in_cw = 0.f, cw1 = 1.f, in_ch = 0.f, ch1 = 1.f, u0 = 0.f, u1 = 0.f;
#pragma unroll
  for (int i = 0; i < 8; i++) {
    if (i == idx) {
      in_cw = cumw[i]; cw1 = cumw[i + 1];
      in_ch = cumh[i]; ch1 = cumh[i + 1];
      u0 = (i > 0) ? bf2f((unsigned short)vd[i - 1]) : 0.0f;
      u1 = (i < 7) ? bf2f((unsigned short)vd[i]) : 0.0f;
    }
  }
  float dd0 = (idx == 0) ? 1.0f
            : MIN_DC + fmaxf(u0, 0.f) + __logf(1.0f + __expf(-fabsf(u0)));
  float dd1 = (idx == 7) ? 1.0f
            : MIN_DC + fmaxf(u1, 0.f) + __logf(1.0f + __expf(-fabsf(u1)));
  float in_w = cw1 - in_cw;
  float in_h = ch1 - in_ch;

  float delta = in_h / in_w;
  float th  = (z_in - in_cw) / in_w;
  float th1 = th * (1.0f - th);
  float th2 = th * th;
  float num = in_h * (delta * th2 + dd0 * th1);
  float den = delta + (dd0 + dd1 - 2.0f * delta) * th1;
  float outz = in_ch + num / den;
  float omt = 1.0f - th;
  float dnum = delta * delta * (dd1 * th2 + 2.0f * delta * th1 + dd0 * omt * omt);
  float l = LN2 * (__log2f(dnum) - 2.0f * __log2f(den));

  zn  = inside ? outz : zv;
  lad = inside ? l : 0.0f;
}

// ---------------- fused GEMM3 + spline, 128x192 tile, 8 WAVES (512 thr) ---------
// grid MUST be (8, 256). Same tile/staging/K-loop math as the R1 67.6us kernel,
// but 8 waves x 64x48 output each (acc[4][3] = 48 VGPR) instead of 4 x 64x96.
// VGPR budget ~125 <= 128 -> __launch_bounds__(512,4) = 4 waves/SIMD at
// 2 blocks/CU -> 2x the latency-hiding of every prior variant (the ONE lever
// the R1-R8 ledger shows matters; gemm3 is latency-bound at 2 waves/SIMD).
// LDS: staging 40KB (A 16 + B 24, linear layouts) unioned with p 51.2KB,
// + 2KB lad-reduce buffer = 53.2KB -> 2 blocks/CU. One atomicAdd per row.

__global__ __launch_bounds__(512, 4) void gemm3_spline(
    const unsigned short* __restrict__ A,     // h2 [B][512] (k degree-permuted)
    const unsigned short* __restrict__ Bw,    // w3c[t] [1536][512] (MPAD rows, perm k)
    const float* __restrict__ bias,           // [1536] (MPAD layout)
    float* __restrict__ curf,                 // [B][64]
    unsigned short* __restrict__ A1,          // [B][320]
    float* __restrict__ out,                  // [B] accumulator (= final output)
    int last)
{
  // staging (shorts): A[2 chunks][128 rows][32] = 8192 | B[2 chunks][192][32] = 12288
  __shared__ alignas(16) union {
    unsigned short stage[20480];
    unsigned short p[128 * PSTRIDE];
  } sm;
  __shared__ float cf[512];

  const int tid  = threadIdx.x;
  const int lane = tid & 63;
  const int wave = tid >> 6;           // 0..7

  const int lin = blockIdx.y * 8 + blockIdx.x;
  const int xcd = lin & 7;
  const int loc = lin >> 3;
  const int m0 = (xcd * 32 + (loc >> 3)) * 128;
  const int bn = loc & 7;
  const int n0 = bn * 192;
  const int Keff = 64 * (bn + 1);      // dims 8bn..8bn+7 need h_deg <= 8bn+7

  const int wm = (wave >> 2) * 64;     // 0 / 64
  const int wn = (wave & 3) * 48;      // 0 / 48 / 96 / 144
  const int fr = lane & 15;
  const int fk = (lane >> 4) * 8;

  // spline mapping: row = tid&127, dim pair = tid>>7 (dims 2dp, 2dp+1)
  const int srow  = tid & 127;
  const int dpair = tid >> 7;          // 0..3
  const int dglob = bn * 8 + dpair * 2;
  float2 cz = *(const float2*)(curf + (size_t)(m0 + srow) * ZD + dglob);

  float bv[3];
#pragma unroll
  for (int j = 0; j < 3; j++) bv[j] = bias[n0 + wn + j * 16 + fr];

  // staging decode (thread-constant byte offsets)
  // A: 1024 16B-units (2 calls): unit u -> chunk=u>>9, within=u&511,
  //    row=within>>2, col16=(within&3). B: 1536 units (3 calls): chunk at 768.
  int aG[2], aL[2], bG[3], bL[3];
#pragma unroll
  for (int q = 0; q < 2; ++q) {
    int u = q * 512 + tid, chunk = u >> 9, w_ = u & 511;
    aG[q] = (w_ >> 2) * 1024 + chunk * 64 + ((w_ & 3) << 4);
    aL[q] = chunk * 8192 + w_ * 16;
  }
#pragma unroll
  for (int q = 0; q < 3; ++q) {
    int u = q * 512 + tid;
    int chunk = (u >= 768) ? 1 : 0;
    int w_ = u - 768 * chunk;
    bG[q] = (w_ >> 2) * 1024 + chunk * 64 + ((w_ & 3) << 4);
    bL[q] = chunk * 12288 + w_ * 16;
  }

  const char* gAb = (const char*)A  + ((size_t)m0 << 10);
  const char* gBb = (const char*)Bw + ((size_t)n0 << 10);
  char* lAb = (char*)sm.stage;           // A at shorts [0, 8192)
  char* lBb = (char*)sm.stage + 16384;   // B at shorts [8192, 20480)

  f32x4 acc[4][3];
#pragma unroll
  for (int i = 0; i < 4; i++)
#pragma unroll
    for (int j = 0; j < 3; j++) acc[i][j] = (f32x4){0.f, 0.f, 0.f, 0.f};

  for (int k0 = 0; k0 < Keff; k0 += 64) {
    const int kb = k0 * 2;
    ASYNC16(gAb + aG[0] + kb, lAb + aL[0]);
    ASYNC16(gAb + aG[1] + kb, lAb + aL[1]);
    ASYNC16(gBb + bG[0] + kb, lBb + bL[0]);
    ASYNC16(gBb + bG[1] + kb, lBb + bL[1]);
    ASYNC16(gBb + bG[2] + kb, lBb + bL[2]);
    __syncthreads();

    s16x8 a0[4], a1[4], b0[3], b1[3];
#pragma unroll
    for (int i = 0; i < 4; i++) {
      const unsigned short* ar = sm.stage + (wm + i * 16 + fr) * 32 + fk;
      a0[i] = *(const s16x8*)(ar);
      a1[i] = *(const s16x8*)(ar + 4096);
    }
#pragma unroll
    for (int j = 0; j < 3; j++) {
      const unsigned short* br = sm.stage + 8192 + (wn + j * 16 + fr) * 32 + fk;
      b0[j] = *(const s16x8*)(br);
      b1[j] = *(const s16x8*)(br + 6144);
    }

#pragma unroll
    for (int i = 0; i < 4; i++)
#pragma unroll
      for (int j = 0; j < 3; j++)
        acc[i][j] = __builtin_amdgcn_mfma_f32_16x16x32_bf16(a0[i], b0[j], acc[i][j], 0, 0, 0);
#pragma unroll
    for (int i = 0; i < 4; i++)
#pragma unroll
      for (int j = 0; j < 3; j++)
        acc[i][j] = __builtin_amdgcn_mfma_f32_16x16x32_bf16(a1[i], b1[j], acc[i][j], 0, 0, 0);
    __syncthreads();
  }

  // accumulator + bias -> pT (bf16, padded stride); loop ended with barrier
#pragma unroll
  for (int j = 0; j < 3; j++) {
    const int col = wn + j * 16 + fr;
#pragma unroll
    for (int i = 0; i < 4; i++) {
      const int rbase = wm + i * 16 + (lane >> 4) * 4;
#pragma unroll
      for (int r = 0; r < 4; r++)
        sm.p[(rbase + r) * PSTRIDE + col] = f2bf(acc[i][j][r] + bv[j]);
    }
  }
  __syncthreads();

  // spline: 1 (row, dim-pair) per thread
  {
    const unsigned short* pp = sm.p + srow * PSTRIDE + dpair * 2 * MPAD;
    float zn0, zn1, l0, l1;
    rq_spline(pp,        cz.x, zn0, l0);
    rq_spline(pp + MPAD, cz.y, zn1, l1);

    const int sbr = m0 + srow;
    *(float2*)(curf + (size_t)sbr * ZD + dglob) = make_float2(zn0, zn1);
    unsigned int pkv = (unsigned int)f2bf(zn0) | ((unsigned int)f2bf(zn1) << 16);
    *(unsigned int*)(A1 + (size_t)sbr * K1 + dglob) = pkv;

    float c = l0 + l1;
    if (last) c -= 0.5f * (zn0 * zn0 + zn1 * zn1);
    cf[srow * 4 + dpair] = c;
  }
  __syncthreads();
  if (tid < 128) {
    const float* c4 = cf + tid * 4;
    atomicAdd(&out[m0 + tid], c4[0] + c4[1] + c4[2] + c4[3]);
  }
}

// ---------------- launch ----------------

extern "C" void kernel_launch(void* const* d_in, const int* in_sizes, int n_in,
                              void* d_out, int out_size, void* d_ws, size_t ws_size,
                              hipStream_t stream)
{
  const float* z  = (const float*)d_in[0];
  const float* x  = (const float*)d_in[1];
  const float* W1 = (const float*)d_in[2];
  const float* b1 = (const float*)d_in[3];
  const float* Wc = (const float*)d_in[4];
  const float* bc = (const float*)d_in[5];
  const float* W2 = (const float*)d_in[6];
  const float* b2 = (const float*)d_in[7];
  const float* W3 = (const float*)d_in[8];
  const float* b3 = (const float*)d_in[9];
  float* out = (float*)d_out;
  char* ws = (char*)d_ws;

  size_t oA1 = 0;
  size_t oH1 = oA1 + (size_t)B_ROWS * K1 * 2;
  size_t oH2 = oH1 + (size_t)B_ROWS * HID * 2;
  size_t oCU = oH2 + (size_t)B_ROWS * HID * 2;
  size_t oW1 = oCU + (size_t)B_ROWS * ZD * 4;
  size_t oW2 = oW1 + (size_t)T_STEPS * HID * K1 * 2;
  size_t oW3 = oW2 + (size_t)T_STEPS * HID * HID * 2;
  size_t oB1 = oW3 + (size_t)T_STEPS * NPAD * HID * 2;
  size_t oB2 = oB1 + (size_t)T_STEPS * HID * 4;
  size_t oB3 = oB2 + (size_t)T_STEPS * HID * 4;

  unsigned short* A1  = (unsigned short*)(ws + oA1);
  unsigned short* h1  = (unsigned short*)(ws + oH1);
  unsigned short* h2  = (unsigned short*)(ws + oH2);
  float* curf = (float*)(ws + oCU);
  unsigned short* w1c = (unsigned short*)(ws + oW1);
  unsigned short* w2c = (unsigned short*)(ws + oW2);
  unsigned short* w3c = (unsigned short*)(ws + oW3);
  float* b1c = (float*)(ws + oB1);
  float* b2p = (float*)(ws + oB2);
  float* b3c = (float*)(ws + oB3);

  const int prepw_total = T_STEPS * (HID * K1 + HID * HID + NPAD * HID + 2 * HID + NPAD);
  prep_weights<<<(prepw_total + 255) / 256, 256, 0, stream>>>(
      W1, Wc, W2, W3, b1, bc, b2, b3, w1c, w2c, w3c, b1c, b2p, b3c);
  const int prepd_total = B_ROWS * (XD + ZD);
  prep_data<<<(prepd_total + 255) / 256, 256, 0, stream>>>(x, z, A1, curf, out);

  for (int t = 0; t < T_STEPS; ++t) {
    gemm_bias<<<dim3(4, B_ROWS / 128), 256, 0, stream>>>(
        A1, w1c + (size_t)t * HID * K1, b1c + (size_t)t * HID, h1,
        B_ROWS, HID, K1, 0, 0);
    gemm_bias<<<dim3(4, B_ROWS / 128), 256, 0, stream>>>(
        h1, w2c + (size_t)t * HID * HID, b2p + (size_t)t * HID, h2,
        B_ROWS, HID, HID, 1, 1);
    gemm3_spline<<<dim3(8, B_ROWS / 128), 512, 0, stream>>>(
        h2, w3c + (size_t)t * NPAD * HID, b3c + (size_t)t * NPAD,
        curf, A1, out, (t == T_STEPS - 1) ? 1 : 0);
  }
}